// Round 1
// baseline (724.572 us; speedup 1.0000x reference)
//
#include <hip/hip_runtime.h>
#include <hip/hip_bf16.h>
#include <math.h>

// Problem constants
#define SEQ 2048
#define EMB 1024
#define NH 16
#define NKVH 8
#define HD 64

typedef __attribute__((ext_vector_type(8))) short short8;
typedef __attribute__((ext_vector_type(4))) float float4v;

static __device__ __forceinline__ float bf2f(ushort u) {
    union { unsigned int i; float f; } v; v.i = ((unsigned int)u) << 16; return v.f;
}
static __device__ __forceinline__ ushort f2bf(float f) {
    union { float f; unsigned int i; } v; v.f = f;
    unsigned int x = v.i;
    return (ushort)((x + 0x7fffu + ((x >> 16) & 1u)) >> 16);
}
static __device__ __forceinline__ float4v mfma16(short8 a, short8 b, float4v c) {
    return __builtin_amdgcn_mfma_f32_16x16x32_bf16(a, b, c, 0, 0, 0);
}

// ---------------------------------------------------------------- converts
__global__ void cvt_f32_bf16(const float* __restrict__ src, ushort* __restrict__ dst, int n) {
    int i = blockIdx.x * 256 + threadIdx.x;
    if (i < n) dst[i] = f2bf(src[i]);
}

// ---------------------------------------------------------------- QKV GEMM
// C[2048][2048] = x16[2048][1024] . Wcat^T ; Wcat rows = [wq(1024), wk(512), wv(512)], all K=1024
__global__ __launch_bounds__(256) void gemm_qkv(
    const ushort* __restrict__ x16,
    const ushort* __restrict__ wq16,
    const ushort* __restrict__ wk16,
    const ushort* __restrict__ wv16,
    float* __restrict__ C)
{
    const int l  = threadIdx.x & 63;
    const int w  = threadIdx.x >> 6;
    const int mt = blockIdx.x;   // 0..31
    const int nt = blockIdx.y;   // 0..31
    const int m0  = mt * 64 + (w & 1) * 32;
    const int n0g = nt * 64 + (w >> 1) * 32;
    const ushort* Wp; int nb;
    if (nt < 16)      { Wp = wq16; nb = n0g; }
    else if (nt < 24) { Wp = wk16; nb = n0g - 1024; }
    else              { Wp = wv16; nb = n0g - 1536; }
    const int lr = l & 15, lq = l >> 4;
    float4v acc[2][2] = {};
    const ushort* ap0 = x16 + (m0 + lr) * 1024 + lq * 8;
    const ushort* ap1 = ap0 + 16 * 1024;
    const ushort* bp0 = Wp + (nb + lr) * 1024 + lq * 8;
    const ushort* bp1 = bp0 + 16 * 1024;
    for (int kk = 0; kk < 1024; kk += 32) {
        short8 a0 = *(const short8*)(ap0 + kk);
        short8 a1 = *(const short8*)(ap1 + kk);
        short8 b0 = *(const short8*)(bp0 + kk);
        short8 b1 = *(const short8*)(bp1 + kk);
        acc[0][0] = mfma16(a0, b0, acc[0][0]);
        acc[0][1] = mfma16(a0, b1, acc[0][1]);
        acc[1][0] = mfma16(a1, b0, acc[1][0]);
        acc[1][1] = mfma16(a1, b1, acc[1][1]);
    }
    for (int i = 0; i < 2; i++)
        for (int j = 0; j < 2; j++)
            for (int r = 0; r < 4; r++) {
                int row = m0 + i * 16 + lq * 4 + r;
                int col = nt * 64 + (w >> 1) * 32 + j * 16 + lr;
                C[row * 2048 + col] = acc[i][j][r];
            }
}

// ---------------------------------------------------------------- bias + RoPE + pack
// q -> qh/ql [H][S][D] (hi/lo bf16 split), k -> kh/kl [KVH][S][D], v -> v16 [S][KVH*D]
__global__ void pack_rope(
    const float* __restrict__ C,
    const float* __restrict__ fcos,  // [S][32]
    const float* __restrict__ fsin,
    const float* __restrict__ wk_b,  // [512]
    const float* __restrict__ wv_b,  // [512]
    ushort* __restrict__ qh, ushort* __restrict__ ql,
    ushort* __restrict__ kh, ushort* __restrict__ kl,
    ushort* __restrict__ v16)
{
    const int s = blockIdx.x;
    const int t = threadIdx.x;
    const float* Cs = C + s * 2048;
    // q: 512 pairs
    for (int p = t; p < 512; p += 256) {
        int h = p >> 5, d2 = p & 31;
        float xr = Cs[h * 64 + 2 * d2];
        float xi = Cs[h * 64 + 2 * d2 + 1];
        float c = fcos[s * 32 + d2], sn = fsin[s * 32 + d2];
        float o0 = xr * c - xi * sn;
        float o1 = xr * sn + xi * c;
        int base = (h * 2048 + s) * 64 + 2 * d2;
        ushort h0 = f2bf(o0), h1 = f2bf(o1);
        qh[base] = h0; qh[base + 1] = h1;
        ql[base]     = f2bf(o0 - bf2f(h0));
        ql[base + 1] = f2bf(o1 - bf2f(h1));
    }
    // k: 256 pairs (bias before rope)
    for (int p = t; p < 256; p += 256) {
        int g = p >> 5, d2 = p & 31;
        float xr = Cs[1024 + g * 64 + 2 * d2]     + wk_b[g * 64 + 2 * d2];
        float xi = Cs[1024 + g * 64 + 2 * d2 + 1] + wk_b[g * 64 + 2 * d2 + 1];
        float c = fcos[s * 32 + d2], sn = fsin[s * 32 + d2];
        float o0 = xr * c - xi * sn;
        float o1 = xr * sn + xi * c;
        int base = (g * 2048 + s) * 64 + 2 * d2;
        ushort h0 = f2bf(o0), h1 = f2bf(o1);
        kh[base] = h0; kh[base + 1] = h1;
        kl[base]     = f2bf(o0 - bf2f(h0));
        kl[base + 1] = f2bf(o1 - bf2f(h1));
    }
    // v: 512 elems (bias, no rope)
    for (int i = t; i < 512; i += 256) {
        v16[s * 512 + i] = f2bf(Cs[1536 + i] + wv_b[i]);
    }
}

// ---------------------------------------------------------------- V transpose: [S][512] -> [512][S]
__global__ void transpose_v(const ushort* __restrict__ v16, ushort* __restrict__ vt) {
    __shared__ ushort tile[64][65];
    const int bx = blockIdx.x;  // 0..7  (col tiles of 512)
    const int by = blockIdx.y;  // 0..31 (row tiles of 2048)
    const int t = threadIdx.x;
    const int tc = t & 63, tr = t >> 6;
    for (int i = 0; i < 64; i += 4)
        tile[tr + i][tc] = v16[(by * 64 + tr + i) * 512 + bx * 64 + tc];
    __syncthreads();
    for (int i = 0; i < 64; i += 4)
        vt[(bx * 64 + tr + i) * 2048 + by * 64 + tc] = tile[tc][tr + i];
}

// ---------------------------------------------------------------- fused attention
// One block = (head h, 16 q-rows). Phase1: split-bf16 QK^T -> clamp -> +bias -> exp -> LDS (swizzled).
// Then rowsum, normalized attn write (fp32, 256MB), PV via MFMA, o16 write.
__global__ __launch_bounds__(256) void attn_kernel(
    const ushort* __restrict__ qh, const ushort* __restrict__ ql,
    const ushort* __restrict__ kh, const ushort* __restrict__ kl,
    const ushort* __restrict__ vt,      // [KVH*64][2048]
    const float* __restrict__ bias,     // [H][S][S]
    float* __restrict__ attn_out,       // [H][S][S]
    ushort* __restrict__ o16,           // [S][E]
    float* __restrict__ rowsum_ws)      // [gridDim.x * 16]
{
    __shared__ ushort e16[16 * 2048];   // 64 KB, XOR-swizzled in 8-elem blocks
    const int blk = blockIdx.x;         // h*128 + qt
    const int h = blk >> 7, qt = blk & 127;
    const int q0 = qt * 16;
    const int g = h >> 1;               // kv head
    const int t = threadIdx.x, l = t & 63, w = t >> 6;
    const int lr = l & 15, lq = l >> 4;

    // Q fragments (16 rows, k-dim = d = 64 -> two 32-chunks), hi+lo
    const ushort* qb  = qh + (h * 2048 + q0 + lr) * 64 + lq * 8;
    const ushort* qlb = ql + (h * 2048 + q0 + lr) * 64 + lq * 8;
    short8 a_h0 = *(const short8*)(qb);
    short8 a_h1 = *(const short8*)(qb + 32);
    short8 a_l0 = *(const short8*)(qlb);
    short8 a_l1 = *(const short8*)(qlb + 32);

    const float* bias_base = bias + ((size_t)(h * 2048 + q0)) * 2048;

    // ---- phase 1: scores -> exp -> LDS
    for (int kt = w * 16; kt < 2048; kt += 64) {
        const ushort* kb  = kh + (g * 2048 + kt + lr) * 64 + lq * 8;
        const ushort* klb = kl + (g * 2048 + kt + lr) * 64 + lq * 8;
        short8 b_h0 = *(const short8*)(kb);
        short8 b_h1 = *(const short8*)(kb + 32);
        short8 b_l0 = *(const short8*)(klb);
        short8 b_l1 = *(const short8*)(klb + 32);
        float4v acc = {};
        acc = mfma16(a_h0, b_h0, acc);
        acc = mfma16(a_h1, b_h1, acc);
        acc = mfma16(a_l0, b_h0, acc);
        acc = mfma16(a_l1, b_h1, acc);
        acc = mfma16(a_h0, b_l0, acc);
        acc = mfma16(a_h1, b_l1, acc);
        for (int r = 0; r < 4; r++) {
            int row = lq * 4 + r;       // local q row
            int col = kt + lr;          // key index
            float sv = acc[r] * 0.125f;
            sv = fminf(fmaxf(sv, -50000.f), 50000.f);
            sv += bias_base[(size_t)row * 2048 + col];
            float e = __expf(sv);
            int sw = ((((col >> 3) ^ (row & 7)) << 3) | (col & 7));
            e16[row * 2048 + sw] = f2bf(e);
        }
    }
    __syncthreads();

    // ---- rowsums from LDS (consistent with stored bf16 e)
    {
        int row = t >> 4, seg = t & 15;
        float rs = 0.f;
        for (int k = 0; k < 128; k++) {
            int col = seg * 128 + k;
            int sw = ((((col >> 3) ^ (row & 7)) << 3) | (col & 7));
            rs += bf2f(e16[row * 2048 + sw]);
        }
        for (int m = 1; m < 16; m <<= 1) rs += __shfl_xor(rs, m, 64);
        if (seg == 0) rowsum_ws[blk * 16 + row] = 1.f / rs;
    }
    __syncthreads();

    // ---- phase 2a: write normalized attention weights (coalesced fp32)
    {
        float* aout = attn_out + ((size_t)(h * 2048 + q0)) * 2048;
        for (int j = 0; j < 128; j++) {
            int idx = j * 256 + t;
            int row = idx >> 11, col = idx & 2047;
            int sw = ((((col >> 3) ^ (row & 7)) << 3) | (col & 7));
            float invs = rowsum_ws[blk * 16 + row];
            aout[(size_t)row * 2048 + col] = bf2f(e16[row * 2048 + sw]) * invs;
        }
    }

    // ---- phase 2b: PV (each wave: 16 q-rows x 16 d-cols, k=2048)
    {
        const int d0 = w * 16;
        const ushort* vb = vt + (g * 64 + d0 + lr) * 2048 + lq * 8;
        float4v acc = {};
        for (int kt = 0; kt < 2048; kt += 32) {
            int blk8 = (kt >> 3) + lq;           // 8-elem block index of A-frag
            short8 a = *(const short8*)(&e16[lr * 2048 + ((blk8 ^ (lr & 7)) << 3)]);
            short8 b = *(const short8*)(vb + kt);
            acc = mfma16(a, b, acc);
        }
        for (int r = 0; r < 4; r++) {
            int row = lq * 4 + r;
            float invs = rowsum_ws[blk * 16 + row];
            o16[(q0 + row) * 1024 + h * 64 + d0 + lr] = f2bf(acc[r] * invs);
        }
    }
}

// ---------------------------------------------------------------- out projection
__global__ __launch_bounds__(256) void gemm_out(
    const ushort* __restrict__ o16,    // 2048 x 1024
    const ushort* __restrict__ wo16,   // 1024 x 1024
    const float* __restrict__ wo_b,    // 1024
    float* __restrict__ out)           // 2048 x 1024
{
    const int l  = threadIdx.x & 63;
    const int w  = threadIdx.x >> 6;
    const int mt = blockIdx.x;  // 0..31
    const int nt = blockIdx.y;  // 0..15
    const int m0 = mt * 64 + (w & 1) * 32;
    const int n0 = nt * 64 + (w >> 1) * 32;
    const int lr = l & 15, lq = l >> 4;
    float4v acc[2][2] = {};
    const ushort* ap0 = o16 + (m0 + lr) * 1024 + lq * 8;
    const ushort* ap1 = ap0 + 16 * 1024;
    const ushort* bp0 = wo16 + (n0 + lr) * 1024 + lq * 8;
    const ushort* bp1 = bp0 + 16 * 1024;
    for (int kk = 0; kk < 1024; kk += 32) {
        short8 a0 = *(const short8*)(ap0 + kk);
        short8 a1 = *(const short8*)(ap1 + kk);
        short8 b0 = *(const short8*)(bp0 + kk);
        short8 b1 = *(const short8*)(bp1 + kk);
        acc[0][0] = mfma16(a0, b0, acc[0][0]);
        acc[0][1] = mfma16(a0, b1, acc[0][1]);
        acc[1][0] = mfma16(a1, b0, acc[1][0]);
        acc[1][1] = mfma16(a1, b1, acc[1][1]);
    }
    for (int i = 0; i < 2; i++)
        for (int j = 0; j < 2; j++)
            for (int r = 0; r < 4; r++) {
                int row = m0 + i * 16 + lq * 4 + r;
                int col = n0 + j * 16 + lr;
                out[row * 1024 + col] = acc[i][j][r] + wo_b[col];
            }
}

// ---------------------------------------------------------------- launch
extern "C" void kernel_launch(void* const* d_in, const int* in_sizes, int n_in,
                              void* d_out, int out_size, void* d_ws, size_t ws_size,
                              hipStream_t stream) {
    const float* x      = (const float*)d_in[0];
    const float* abias  = (const float*)d_in[1];
    const float* fcos   = (const float*)d_in[2];
    const float* fsin   = (const float*)d_in[3];
    const float* wq_w   = (const float*)d_in[4];
    const float* wk_w   = (const float*)d_in[5];
    const float* wk_b   = (const float*)d_in[6];
    const float* wv_w   = (const float*)d_in[7];
    const float* wv_b   = (const float*)d_in[8];
    const float* wo_w   = (const float*)d_in[9];
    const float* wo_b   = (const float*)d_in[10];

    float* out_proj = (float*)d_out;                       // 2048*1024
    float* out_attn = (float*)d_out + (size_t)2048 * 1024; // 16*2048*2048

    char* ws = (char*)d_ws;
    const size_t MB = 1024 * 1024;
    ushort* x16  = (ushort*)(ws + 0 * MB);   // 4 MB
    ushort* wq16 = (ushort*)(ws + 4 * MB);   // 2 MB
    ushort* wk16 = (ushort*)(ws + 6 * MB);   // 1 MB
    ushort* wv16 = (ushort*)(ws + 7 * MB);   // 1 MB
    ushort* wo16 = (ushort*)(ws + 8 * MB);   // 2 MB
    float*  Cqkv = (float*) (ws + 10 * MB);  // 16 MB
    ushort* qh   = (ushort*)(ws + 26 * MB);  // 4 MB
    ushort* qlb  = (ushort*)(ws + 30 * MB);  // 4 MB
    ushort* kh   = (ushort*)(ws + 34 * MB);  // 2 MB
    ushort* klb  = (ushort*)(ws + 36 * MB);  // 2 MB
    ushort* v16  = (ushort*)(ws + 38 * MB);  // 2 MB
    ushort* vt   = (ushort*)(ws + 40 * MB);  // 2 MB
    ushort* o16  = (ushort*)(ws + 42 * MB);  // 4 MB
    float*  rsum = (float*) (ws + 46 * MB);  // 128 KB

    // converts
    cvt_f32_bf16<<<(2048 * 1024 + 255) / 256, 256, 0, stream>>>(x, x16, 2048 * 1024);
    cvt_f32_bf16<<<(1024 * 1024 + 255) / 256, 256, 0, stream>>>(wq_w, wq16, 1024 * 1024);
    cvt_f32_bf16<<<(512 * 1024 + 255) / 256, 256, 0, stream>>>(wk_w, wk16, 512 * 1024);
    cvt_f32_bf16<<<(512 * 1024 + 255) / 256, 256, 0, stream>>>(wv_w, wv16, 512 * 1024);
    cvt_f32_bf16<<<(1024 * 1024 + 255) / 256, 256, 0, stream>>>(wo_w, wo16, 1024 * 1024);

    // QKV projection
    gemm_qkv<<<dim3(32, 32), 256, 0, stream>>>(x16, wq16, wk16, wv16, Cqkv);

    // bias + rope + pack
    pack_rope<<<2048, 256, 0, stream>>>(Cqkv, fcos, fsin, wk_b, wv_b, qh, qlb, kh, klb, v16);

    // V transpose
    transpose_v<<<dim3(8, 32), 256, 0, stream>>>(v16, vt);

    // fused attention
    attn_kernel<<<NH * 128, 256, 0, stream>>>(qh, qlb, kh, klb, vt, abias, out_attn, o16, rsum);

    // out projection
    gemm_out<<<dim3(32, 16), 256, 0, stream>>>(o16, wo16, wo_b, out_proj);
}

// Round 2
// 711.480 us; speedup vs baseline: 1.0184x; 1.0184x over previous
//
#include <hip/hip_runtime.h>
#include <hip/hip_bf16.h>
#include <math.h>

#define SEQ 2048
#define EMB 1024
#define NH 16
#define NKVH 8
#define HD 64

typedef __attribute__((ext_vector_type(8))) short short8;
typedef __attribute__((ext_vector_type(4))) float float4v;
typedef __attribute__((ext_vector_type(4))) unsigned short ushort4v;

static __device__ __forceinline__ float bf2f(ushort u) {
    union { unsigned int i; float f; } v; v.i = ((unsigned int)u) << 16; return v.f;
}
static __device__ __forceinline__ ushort f2bf(float f) {
    union { float f; unsigned int i; } v; v.f = f;
    unsigned int x = v.i;
    return (ushort)((x + 0x7fffu + ((x >> 16) & 1u)) >> 16);
}
static __device__ __forceinline__ float4v mfma16(short8 a, short8 b, float4v c) {
    return __builtin_amdgcn_mfma_f32_16x16x32_bf16(a, b, c, 0, 0, 0);
}

// ---------------------------------------------------------------- fused converts
// float4-index layout: x 524288 | wq 262144 | wk 131072 | wv 131072 | wo 262144
__global__ void cvt_all(const float* __restrict__ x, const float* __restrict__ wq,
                        const float* __restrict__ wk, const float* __restrict__ wv,
                        const float* __restrict__ wo,
                        ushort* __restrict__ x16, ushort* __restrict__ wq16,
                        ushort* __restrict__ wk16, ushort* __restrict__ wv16,
                        ushort* __restrict__ wo16)
{
    int i = blockIdx.x * 256 + threadIdx.x;    // float4 index, < 1310720
    const float* s; ushort* d; int off;
    if (i < 524288)       { s = x;  d = x16;  off = i; }
    else if (i < 786432)  { s = wq; d = wq16; off = i - 524288; }
    else if (i < 917504)  { s = wk; d = wk16; off = i - 786432; }
    else if (i < 1048576) { s = wv; d = wv16; off = i - 917504; }
    else                  { s = wo; d = wo16; off = i - 1048576; }
    float4v v = *(const float4v*)(s + (size_t)off * 4);
    ushort4v u;
    u.x = f2bf(v.x); u.y = f2bf(v.y); u.z = f2bf(v.z); u.w = f2bf(v.w);
    *(ushort4v*)(d + (size_t)off * 4) = u;
}

// ---------------------------------------------------------------- QKV GEMM
__global__ __launch_bounds__(256) void gemm_qkv(
    const ushort* __restrict__ x16,
    const ushort* __restrict__ wq16,
    const ushort* __restrict__ wk16,
    const ushort* __restrict__ wv16,
    float* __restrict__ C)
{
    const int l  = threadIdx.x & 63;
    const int w  = threadIdx.x >> 6;
    const int mt = blockIdx.x;   // 0..31
    const int nt = blockIdx.y;   // 0..31
    const int m0  = mt * 64 + (w & 1) * 32;
    const int n0g = nt * 64 + (w >> 1) * 32;
    const ushort* Wp; int nb;
    if (nt < 16)      { Wp = wq16; nb = n0g; }
    else if (nt < 24) { Wp = wk16; nb = n0g - 1024; }
    else              { Wp = wv16; nb = n0g - 1536; }
    const int lr = l & 15, lq = l >> 4;
    float4v acc[2][2] = {};
    const ushort* ap0 = x16 + (m0 + lr) * 1024 + lq * 8;
    const ushort* ap1 = ap0 + 16 * 1024;
    const ushort* bp0 = Wp + (nb + lr) * 1024 + lq * 8;
    const ushort* bp1 = bp0 + 16 * 1024;
    for (int kk = 0; kk < 1024; kk += 32) {
        short8 a0 = *(const short8*)(ap0 + kk);
        short8 a1 = *(const short8*)(ap1 + kk);
        short8 b0 = *(const short8*)(bp0 + kk);
        short8 b1 = *(const short8*)(bp1 + kk);
        acc[0][0] = mfma16(a0, b0, acc[0][0]);
        acc[0][1] = mfma16(a0, b1, acc[0][1]);
        acc[1][0] = mfma16(a1, b0, acc[1][0]);
        acc[1][1] = mfma16(a1, b1, acc[1][1]);
    }
    for (int i = 0; i < 2; i++)
        for (int j = 0; j < 2; j++)
            for (int r = 0; r < 4; r++) {
                int row = m0 + i * 16 + lq * 4 + r;
                int col = nt * 64 + (w >> 1) * 32 + j * 16 + lr;
                C[row * 2048 + col] = acc[i][j][r];
            }
}

// ---------------------------------------------------------------- bias + RoPE + pack
__global__ void pack_rope(
    const float* __restrict__ C,
    const float* __restrict__ fcos,
    const float* __restrict__ fsin,
    const float* __restrict__ wk_b,
    const float* __restrict__ wv_b,
    ushort* __restrict__ qh, ushort* __restrict__ ql,
    ushort* __restrict__ kh, ushort* __restrict__ kl,
    ushort* __restrict__ v16)
{
    const int s = blockIdx.x;
    const int t = threadIdx.x;
    const float* Cs = C + s * 2048;
    for (int p = t; p < 512; p += 256) {
        int h = p >> 5, d2 = p & 31;
        float xr = Cs[h * 64 + 2 * d2];
        float xi = Cs[h * 64 + 2 * d2 + 1];
        float c = fcos[s * 32 + d2], sn = fsin[s * 32 + d2];
        float o0 = xr * c - xi * sn;
        float o1 = xr * sn + xi * c;
        int base = (h * 2048 + s) * 64 + 2 * d2;
        ushort h0 = f2bf(o0), h1 = f2bf(o1);
        qh[base] = h0; qh[base + 1] = h1;
        ql[base]     = f2bf(o0 - bf2f(h0));
        ql[base + 1] = f2bf(o1 - bf2f(h1));
    }
    for (int p = t; p < 256; p += 256) {
        int g = p >> 5, d2 = p & 31;
        float xr = Cs[1024 + g * 64 + 2 * d2]     + wk_b[g * 64 + 2 * d2];
        float xi = Cs[1024 + g * 64 + 2 * d2 + 1] + wk_b[g * 64 + 2 * d2 + 1];
        float c = fcos[s * 32 + d2], sn = fsin[s * 32 + d2];
        float o0 = xr * c - xi * sn;
        float o1 = xr * sn + xi * c;
        int base = (g * 2048 + s) * 64 + 2 * d2;
        ushort h0 = f2bf(o0), h1 = f2bf(o1);
        kh[base] = h0; kh[base + 1] = h1;
        kl[base]     = f2bf(o0 - bf2f(h0));
        kl[base + 1] = f2bf(o1 - bf2f(h1));
    }
    for (int i = t; i < 512; i += 256) {
        v16[s * 512 + i] = f2bf(Cs[1536 + i] + wv_b[i]);
    }
}

// ---------------------------------------------------------------- V transpose
__global__ void transpose_v(const ushort* __restrict__ v16, ushort* __restrict__ vt) {
    __shared__ ushort tile[64][65];
    const int bx = blockIdx.x;
    const int by = blockIdx.y;
    const int t = threadIdx.x;
    const int tc = t & 63, tr = t >> 6;
    for (int i = 0; i < 64; i += 4)
        tile[tr + i][tc] = v16[(by * 64 + tr + i) * 512 + bx * 64 + tc];
    __syncthreads();
    for (int i = 0; i < 64; i += 4)
        vt[(bx * 64 + tr + i) * 2048 + by * 64 + tc] = tile[tc][tr + i];
}

// ---------------------------------------------------------------- fused attention (v2)
// 512 threads (8 waves). Phase1: 8 waves split the 128 key-tiles.
// Rowsum vectorized. Phase2: waves 0-3 PV (MFMA) || waves 4-7 attn-weight stream.
__global__ __launch_bounds__(512) void attn_kernel(
    const ushort* __restrict__ qh, const ushort* __restrict__ ql,
    const ushort* __restrict__ kh, const ushort* __restrict__ kl,
    const ushort* __restrict__ vt,
    const float* __restrict__ bias,
    float* __restrict__ attn_out,
    ushort* __restrict__ o16)
{
    __shared__ ushort e16[16 * 2048];   // 64 KB, XOR-swizzled in 8-elem blocks
    __shared__ float invs_s[16];
    const int blk = blockIdx.x;         // h*128 + qt
    const int h = blk >> 7, qt = blk & 127;
    const int q0 = qt * 16;
    const int g = h >> 1;
    const int t = threadIdx.x, l = t & 63, w = t >> 6;  // w: 0..7
    const int lr = l & 15, lq = l >> 4;

    const ushort* qb  = qh + (h * 2048 + q0 + lr) * 64 + lq * 8;
    const ushort* qlb = ql + (h * 2048 + q0 + lr) * 64 + lq * 8;
    short8 a_h0 = *(const short8*)(qb);
    short8 a_h1 = *(const short8*)(qb + 32);
    short8 a_l0 = *(const short8*)(qlb);
    short8 a_l1 = *(const short8*)(qlb + 32);

    const float* bias_base = bias + ((size_t)(h * 2048 + q0)) * 2048;

    // ---- phase 1: scores -> exp -> LDS (each wave: 16 of 128 key-tiles)
    for (int kt = w * 16; kt < 2048; kt += 128) {
        const ushort* kb  = kh + (g * 2048 + kt + lr) * 64 + lq * 8;
        const ushort* klb = kl + (g * 2048 + kt + lr) * 64 + lq * 8;
        short8 b_h0 = *(const short8*)(kb);
        short8 b_h1 = *(const short8*)(kb + 32);
        short8 b_l0 = *(const short8*)(klb);
        short8 b_l1 = *(const short8*)(klb + 32);
        float4v acc = {};
        acc = mfma16(a_h0, b_h0, acc);
        acc = mfma16(a_h1, b_h1, acc);
        acc = mfma16(a_l0, b_h0, acc);
        acc = mfma16(a_l1, b_h1, acc);
        acc = mfma16(a_h0, b_l0, acc);
        acc = mfma16(a_h1, b_l1, acc);
        for (int r = 0; r < 4; r++) {
            int row = lq * 4 + r;
            int col = kt + lr;
            float sv = acc[r] * 0.125f;
            sv = fminf(fmaxf(sv, -50000.f), 50000.f);
            sv += bias_base[(size_t)row * 2048 + col];
            float e = __expf(sv);
            int sw = ((((col >> 3) ^ (row & 7)) << 3) | (col & 7));
            e16[row * 2048 + sw] = f2bf(e);
        }
    }
    __syncthreads();

    // ---- rowsum (vectorized): 32 threads per row, 8 x short8 each
    {
        int row = t >> 5, c32 = t & 31;
        float rs = 0.f;
        for (int j = 0; j < 8; j++) {
            int cb = c32 * 8 + j;  // col-block 0..255
            short8 e = *(const short8*)(&e16[row * 2048 + ((cb ^ (row & 7)) << 3)]);
            for (int u = 0; u < 8; u++) rs += bf2f(e[u]);
        }
        rs += __shfl_xor(rs, 1, 64);
        rs += __shfl_xor(rs, 2, 64);
        rs += __shfl_xor(rs, 4, 64);
        rs += __shfl_xor(rs, 8, 64);
        rs += __shfl_xor(rs, 16, 64);
        if (c32 == 0) invs_s[row] = 1.f / rs;
    }
    __syncthreads();

    if (w < 4) {
        // ---- PV: wave w covers d-cols [w*16, w*16+16)
        const int d0 = w * 16;
        const ushort* vb = vt + (g * 64 + d0 + lr) * 2048 + lq * 8;
        float4v acc = {};
        for (int kt = 0; kt < 2048; kt += 32) {
            int blk8 = (kt >> 3) + lq;
            short8 a = *(const short8*)(&e16[lr * 2048 + ((blk8 ^ (lr & 7)) << 3)]);
            short8 b = *(const short8*)(vb + kt);
            acc = mfma16(a, b, acc);
        }
        for (int r = 0; r < 4; r++) {
            int row = lq * 4 + r;
            o16[(q0 + row) * 1024 + h * 64 + d0 + lr] = f2bf(acc[r] * invs_s[row]);
        }
    } else {
        // ---- attn-weight stream: 256 threads, one full row (8 KB) per iter
        float* aout = attn_out + ((size_t)(h * 2048 + q0)) * 2048;
        const int t2 = t - 256;  // 0..255
        for (int row = 0; row < 16; row++) {
            short8 e = *(const short8*)(&e16[row * 2048 + ((t2 ^ (row & 7)) << 3)]);
            float invs = invs_s[row];
            float4v o0, o1;
            o0.x = bf2f(e[0]) * invs; o0.y = bf2f(e[1]) * invs;
            o0.z = bf2f(e[2]) * invs; o0.w = bf2f(e[3]) * invs;
            o1.x = bf2f(e[4]) * invs; o1.y = bf2f(e[5]) * invs;
            o1.z = bf2f(e[6]) * invs; o1.w = bf2f(e[7]) * invs;
            float* p = aout + (size_t)row * 2048 + t2 * 8;
            *(float4v*)(p) = o0;
            *(float4v*)(p + 4) = o1;
        }
    }
}

// ---------------------------------------------------------------- out projection
__global__ __launch_bounds__(256) void gemm_out(
    const ushort* __restrict__ o16,
    const ushort* __restrict__ wo16,
    const float* __restrict__ wo_b,
    float* __restrict__ out)
{
    const int l  = threadIdx.x & 63;
    const int w  = threadIdx.x >> 6;
    const int mt = blockIdx.x;
    const int nt = blockIdx.y;
    const int m0 = mt * 64 + (w & 1) * 32;
    const int n0 = nt * 64 + (w >> 1) * 32;
    const int lr = l & 15, lq = l >> 4;
    float4v acc[2][2] = {};
    const ushort* ap0 = o16 + (m0 + lr) * 1024 + lq * 8;
    const ushort* ap1 = ap0 + 16 * 1024;
    const ushort* bp0 = wo16 + (n0 + lr) * 1024 + lq * 8;
    const ushort* bp1 = bp0 + 16 * 1024;
    for (int kk = 0; kk < 1024; kk += 32) {
        short8 a0 = *(const short8*)(ap0 + kk);
        short8 a1 = *(const short8*)(ap1 + kk);
        short8 b0 = *(const short8*)(bp0 + kk);
        short8 b1 = *(const short8*)(bp1 + kk);
        acc[0][0] = mfma16(a0, b0, acc[0][0]);
        acc[0][1] = mfma16(a0, b1, acc[0][1]);
        acc[1][0] = mfma16(a1, b0, acc[1][0]);
        acc[1][1] = mfma16(a1, b1, acc[1][1]);
    }
    for (int i = 0; i < 2; i++)
        for (int j = 0; j < 2; j++)
            for (int r = 0; r < 4; r++) {
                int row = m0 + i * 16 + lq * 4 + r;
                int col = n0 + j * 16 + lr;
                out[row * 1024 + col] = acc[i][j][r] + wo_b[col];
            }
}

// ---------------------------------------------------------------- launch
extern "C" void kernel_launch(void* const* d_in, const int* in_sizes, int n_in,
                              void* d_out, int out_size, void* d_ws, size_t ws_size,
                              hipStream_t stream) {
    const float* x      = (const float*)d_in[0];
    const float* abias  = (const float*)d_in[1];
    const float* fcos   = (const float*)d_in[2];
    const float* fsin   = (const float*)d_in[3];
    const float* wq_w   = (const float*)d_in[4];
    const float* wk_w   = (const float*)d_in[5];
    const float* wk_b   = (const float*)d_in[6];
    const float* wv_w   = (const float*)d_in[7];
    const float* wv_b   = (const float*)d_in[8];
    const float* wo_w   = (const float*)d_in[9];
    const float* wo_b   = (const float*)d_in[10];

    float* out_proj = (float*)d_out;
    float* out_attn = (float*)d_out + (size_t)2048 * 1024;

    char* ws = (char*)d_ws;
    const size_t MB = 1024 * 1024;
    ushort* x16  = (ushort*)(ws + 0 * MB);
    ushort* wq16 = (ushort*)(ws + 4 * MB);
    ushort* wk16 = (ushort*)(ws + 6 * MB);
    ushort* wv16 = (ushort*)(ws + 7 * MB);
    ushort* wo16 = (ushort*)(ws + 8 * MB);
    float*  Cqkv = (float*) (ws + 10 * MB);
    ushort* qh   = (ushort*)(ws + 26 * MB);
    ushort* qlb  = (ushort*)(ws + 30 * MB);
    ushort* kh   = (ushort*)(ws + 34 * MB);
    ushort* klb  = (ushort*)(ws + 36 * MB);
    ushort* v16  = (ushort*)(ws + 38 * MB);
    ushort* vt   = (ushort*)(ws + 40 * MB);
    ushort* o16  = (ushort*)(ws + 42 * MB);

    cvt_all<<<5120, 256, 0, stream>>>(x, wq_w, wk_w, wv_w, wo_w,
                                      x16, wq16, wk16, wv16, wo16);
    gemm_qkv<<<dim3(32, 32), 256, 0, stream>>>(x16, wq16, wk16, wv16, Cqkv);
    pack_rope<<<2048, 256, 0, stream>>>(Cqkv, fcos, fsin, wk_b, wv_b, qh, qlb, kh, klb, v16);
    transpose_v<<<dim3(8, 32), 256, 0, stream>>>(v16, vt);
    attn_kernel<<<NH * 128, 512, 0, stream>>>(qh, qlb, kh, klb, vt, abias, out_attn, o16);
    gemm_out<<<dim3(32, 16), 256, 0, stream>>>(o16, wo16, wo_b, out_proj);
}